// Round 3
// baseline (744.958 us; speedup 1.0000x reference)
//
#include <hip/hip_runtime.h>

typedef __attribute__((ext_vector_type(8))) __bf16 bf16x8;
typedef __attribute__((ext_vector_type(4))) float f32x4;

#define SCALE_Q 0.17677669529663687f

// np.nonzero of the rolled-window validity mask (4 x 7x7, E=3), ascending.
__constant__ int VALID_IND_C[132] = {
  4,5,6, 11,12,13, 18,19,20, 25,26,27,
  28,29,30,31,32,33,34, 35,36,37,38,39,40,41, 42,43,44,45,46,47,48,
  49,50,51, 56,57,58, 63,64,65, 70,71,72,
  77,78,79,80,81,82,83, 84,85,86,87,88,89,90, 91,92,93,94,95,96,97,
  98,99,100,101,102,103,104, 105,106,107,108,109,110,111, 112,113,114,115,116,117,118,
  123,124,125, 130,131,132, 137,138,139, 144,145,146,
  147,148,149,150,151,152,153, 154,155,156,157,158,159,160, 161,162,163,164,165,166,167,
  168,169,170, 175,176,177, 182,183,184, 189,190,191
};

__device__ __forceinline__ unsigned short f2bf(float f) {
  unsigned int u = __float_as_uint(f);
  u += 0x7fffu + ((u >> 16) & 1u);   // RNE; inputs finite
  return (unsigned short)(u >> 16);
}

__device__ __forceinline__ uint4 pack8(const float4 a, const float4 b) {
  uint4 r;
  r.x = (unsigned)f2bf(a.x) | ((unsigned)f2bf(a.y) << 16);
  r.y = (unsigned)f2bf(a.z) | ((unsigned)f2bf(a.w) << 16);
  r.z = (unsigned)f2bf(b.x) | ((unsigned)f2bf(b.y) << 16);
  r.w = (unsigned)f2bf(b.z) | ((unsigned)f2bf(b.w) << 16);
  return r;
}

// ---------------- prep: pack weights frag-major ----------------
// Wp[((cf*8+ks)*64+lane)*8+e] = W[cf*16+(lane&15)][ks*32+(lane>>4)*8+e]
__global__ void prep_weights(const float* __restrict__ qw, const float* __restrict__ kw,
                             const float* __restrict__ vw, const float* __restrict__ pw,
                             unsigned short* __restrict__ wp) {
  int gid = blockIdx.x * 256 + threadIdx.x;          // 0 .. 262143
  int wsel = gid >> 16;
  int d = gid & 65535;
  const float* W = wsel == 0 ? qw : wsel == 1 ? kw : wsel == 2 ? vw : pw;
  int e = d & 7, ln = (d >> 3) & 63, ks = (d >> 9) & 7, cf = d >> 12;
  int c = cf * 16 + (ln & 15);
  int k = ks * 32 + ((ln >> 4) << 3) + e;
  wp[gid] = f2bf(W[c * 256 + k]);
}

// ---------------- prep: bias_packed[h][key(256)][q(64)] ----------------
__global__ void prep_bias(const float* __restrict__ rpb, const float* __restrict__ rpbp,
                          float* __restrict__ biasp) {
  int idx = blockIdx.x * 256 + threadIdx.x;          // 0 .. 131071
  int q = idx & 63, key = (idx >> 6) & 255, h = idx >> 14;
  int qc = q < 49 ? q : 48;
  float v;
  if (key < 181)      v = rpb[(h * 49 + qc) * 181 + key];
  else if (key < 230) v = rpbp[(h * 49 + qc) * 49 + (key - 181)];
  else                v = -1e30f;
  biasp[idx] = v;
}

// window w, window-local row l (0..255; >=230 clamped) -> source row (256 floats)
__device__ __forceinline__ const float* kv_src_row(int w, int l, const float* x,
                                                   const float* xe, const float* xp) {
  if (l >= 230) l = 229;
  if (l < 49) {
    int b = w >> 8, win = w & 255;
    int wy = win >> 4, wx = win & 15;
    int iy = l / 7, ix = l - iy * 7;
    return x + (((b * 112 + wy * 7 + iy) * 112) + wx * 7 + ix) * 256;
  } else if (l < 181) {
    return xe + (w * 196 + VALID_IND_C[l - 49]) * 256;
  } else {
    return xp + (w * 49 + (l - 181)) * 256;
  }
}

// GEMM core: acc[4][4] += Stile(64x256 bf16, LDS stride 528B) @ Wp^T (4 nfrags)
__device__ __forceinline__ void gemm_core(const char* smem, const unsigned short* Wp,
                                          int nfbase, int lane, f32x4 acc[4][4]) {
  int arow = lane & 15, ahi = lane >> 4;
#pragma unroll
  for (int ks = 0; ks < 8; ++ks) {
    bf16x8 a[4];
#pragma unroll
    for (int m = 0; m < 4; ++m)
      a[m] = *(const bf16x8*)(smem + (m * 16 + arow) * 528 + ks * 64 + ahi * 16);
#pragma unroll
    for (int n = 0; n < 4; ++n) {
      bf16x8 b = *(const bf16x8*)(Wp + (((nfbase + n) * 8 + ks) * 64 + lane) * 8);
#pragma unroll
      for (int m = 0; m < 4; ++m)
        acc[m][n] = __builtin_amdgcn_mfma_f32_16x16x32_bf16(a[m], b, acc[m][n], 0, 0, 0);
    }
  }
}

// ---------------- K & V projection (fused), window-aligned 64-row tiles ----------------
// grid = 1024 windows * 4 sub-tiles; rows l = sub*64 .. sub*64+63 (l>=230 are pad).
__global__ __launch_bounds__(512, 4) void kv_gemm(
    const float* __restrict__ x, const float* __restrict__ xe, const float* __restrict__ xp,
    const float* __restrict__ kb, const float* __restrict__ vb,
    const unsigned short* __restrict__ WpK, const unsigned short* __restrict__ WpV,
    unsigned short* __restrict__ Kg, unsigned short* __restrict__ Vtg) {
  __shared__ char smem[64 * 528];    // A-tile staging, then K output tile [key][c]
  __shared__ char tbuf[256 * 144];   // V output tile [c][key], 128B data + 16B pad
  int tid = threadIdx.x;
  int w = blockIdx.x >> 2, sub = blockIdx.x & 3;
  {
    int r = tid >> 3, seg = tid & 7;   // 32 floats per thread
    const float* src = kv_src_row(w, sub * 64 + r, x, xe, xp) + seg * 32;
    char* dst = smem + r * 528 + seg * 64;
#pragma unroll
    for (int i = 0; i < 4; ++i) {
      float4 a = ((const float4*)src)[i * 2];
      float4 b = ((const float4*)src)[i * 2 + 1];
      *(uint4*)(dst + i * 16) = pack8(a, b);
    }
  }
  __syncthreads();
  int lane = tid & 63, wv = tid >> 6;
  bool isV = wv >= 4;
  int colq = wv & 3;
  const unsigned short* Wp = isV ? WpV : WpK;
  f32x4 acc[4][4];
#pragma unroll
  for (int m = 0; m < 4; ++m)
#pragma unroll
    for (int n = 0; n < 4; ++n) acc[m][n] = (f32x4){0.f, 0.f, 0.f, 0.f};
  gemm_core(smem, Wp, colq * 4, lane, acc);

  int arow = lane & 15, ahi = lane >> 4;
  const float* bias = isV ? vb : kb;
  __syncthreads();   // all A-tile reads done; smem reusable
  if (!isV) {        // K tile -> smem [key_local][c] (stride 528)
#pragma unroll
    for (int n = 0; n < 4; ++n) {
      int c = colq * 64 + n * 16 + arow;
      float bc = bias[c];
#pragma unroll
      for (int m = 0; m < 4; ++m)
#pragma unroll
        for (int reg = 0; reg < 4; ++reg)
          *(unsigned short*)(smem + (m * 16 + ahi * 4 + reg) * 528 + c * 2) =
              f2bf(acc[m][n][reg] + bc);
    }
  } else {           // V tile -> tbuf [c][key_local] (stride 144)
#pragma unroll
    for (int n = 0; n < 4; ++n) {
      int c = colq * 64 + n * 16 + arow;
      float bc = bias[c];
#pragma unroll
      for (int m = 0; m < 4; ++m)
#pragma unroll
        for (int reg = 0; reg < 4; ++reg)
          *(unsigned short*)(tbuf + c * 144 + (m * 16 + ahi * 4 + reg) * 2) =
              f2bf(acc[m][n][reg] + bc);
    }
  }
  __syncthreads();
  { // K copy-out: 64 rows x 512B, coalesced (keys >=230 are benign garbage)
    int r = tid >> 3, seg = tid & 7;
    unsigned short* dst = Kg + (unsigned)(w * 256 + sub * 64 + r) * 256 + seg * 32;
    const char* s = smem + r * 528 + seg * 64;
#pragma unroll
    for (int i = 0; i < 4; ++i) *(uint4*)(dst + i * 8) = *(const uint4*)(s + i * 16);
  }
  { // V copy-out: 256 c-rows x 128B, coalesced
    int c = tid >> 1, hf = tid & 1;
    unsigned short* dst = Vtg + (unsigned)(w * 256 + c) * 256 + sub * 64 + hf * 32;
    const char* s = tbuf + c * 144 + hf * 64;
#pragma unroll
    for (int i = 0; i < 4; ++i) *(uint4*)(dst + i * 8) = *(const uint4*)(s + i * 16);
  }
}

// ---------------- Q projection (per-window, padded to 64 rows), 256 thr ----------------
__global__ __launch_bounds__(256, 4) void q_gemm(
    const float* __restrict__ x, const float* __restrict__ qb,
    const unsigned short* __restrict__ WpQ, unsigned short* __restrict__ Qg) {
  __shared__ char smem[64 * 528];
  int tid = threadIdx.x;
  int w = blockIdx.x;
  int b = w >> 8, win = w & 255, wy = win >> 4, wx = win & 15;
  {
    int r = tid >> 2, seg = tid & 3;   // 64 floats per thread
    int rr = r < 49 ? r : 48;          // clamp pad rows
    int iy = rr / 7, ix = rr - iy * 7;
    const float* src = x + (((b * 112 + wy * 7 + iy) * 112) + wx * 7 + ix) * 256 + seg * 64;
    char* dst = smem + r * 528 + seg * 128;
#pragma unroll
    for (int i = 0; i < 8; ++i) {
      float4 a = ((const float4*)src)[i * 2];
      float4 bb = ((const float4*)src)[i * 2 + 1];
      *(uint4*)(dst + i * 16) = pack8(a, bb);
    }
  }
  __syncthreads();
  int lane = tid & 63, wv = tid >> 6;
  f32x4 acc[4][4];
#pragma unroll
  for (int m = 0; m < 4; ++m)
#pragma unroll
    for (int n = 0; n < 4; ++n) acc[m][n] = (f32x4){0.f, 0.f, 0.f, 0.f};
  gemm_core(smem, WpQ, wv * 4, lane, acc);

  int arow = lane & 15, ahi = lane >> 4;
  __syncthreads();
#pragma unroll
  for (int n = 0; n < 4; ++n) {
    int c = wv * 64 + n * 16 + arow;
    float bc = qb[c];
#pragma unroll
    for (int m = 0; m < 4; ++m)
#pragma unroll
      for (int reg = 0; reg < 4; ++reg)
        *(unsigned short*)(smem + (m * 16 + ahi * 4 + reg) * 528 + c * 2) =
            f2bf((acc[m][n][reg] + bc) * SCALE_Q);
  }
  __syncthreads();
  {
    int r = tid >> 2, seg = tid & 3;
    unsigned short* dst = Qg + (unsigned)(w * 64 + r) * 256 + seg * 64;
    const char* s = smem + r * 528 + seg * 128;
#pragma unroll
    for (int i = 0; i < 8; ++i) *(uint4*)(dst + i * 8) = *(const uint4*)(s + i * 16);
  }
}

// ---------------- fused attention: 1 block/window, wave = head ----------------
__global__ __launch_bounds__(512, 2) void attn_kernel(
    const unsigned short* __restrict__ Qg, const unsigned short* __restrict__ Kg,
    const unsigned short* __restrict__ Vtg, const float* __restrict__ biasp,
    const float* __restrict__ maskp, unsigned short* __restrict__ Og) {
  __shared__ char sK[64 * 528];       // K chunk [64 keys][256 c]
  __shared__ char sV[256 * 144];      // Vt chunk [256 c][64 keys + pad]
  __shared__ char sP[8 * 64 * 144];   // per-wave P [64 q][64 keys + pad] bf16
  int tid = threadIdx.x, lane = tid & 63, h = tid >> 6;
  int w = blockIdx.x, win = w & 255;
  int arow = lane & 15, ahi = lane >> 4;

  bf16x8 qa[4];
#pragma unroll
  for (int m = 0; m < 4; ++m)
    qa[m] = *(const bf16x8*)(Qg + (unsigned)(w * 64 + m * 16 + arow) * 256 + h * 32 + ahi * 8);

  f32x4 o[4][2];
  float mrun[4][4], lrun[4][4];
#pragma unroll
  for (int m = 0; m < 4; ++m) {
#pragma unroll
    for (int r = 0; r < 4; ++r) { mrun[m][r] = -1e30f; lrun[m][r] = 0.f; }
    o[m][0] = (f32x4){0.f, 0.f, 0.f, 0.f};
    o[m][1] = (f32x4){0.f, 0.f, 0.f, 0.f};
  }
  char* myP = sP + h * 9216;

  for (int t = 0; t < 4; ++t) {
    int kb = t * 64;
    __syncthreads();
    { // stage K chunk (all 256 key slots are initialized global data)
      int r = tid >> 3, seg = tid & 7;
      const unsigned short* src = Kg + (unsigned)(w * 256 + kb + r) * 256 + seg * 32;
      char* dst = sK + r * 528 + seg * 64;
#pragma unroll
      for (int i = 0; i < 4; ++i) *(uint4*)(dst + i * 16) = *(const uint4*)(src + i * 8);
      // stage Vt chunk
      int c = tid >> 1, hf = tid & 1;
      const unsigned short* vs = Vtg + (unsigned)(w * 256 + c) * 256 + kb + hf * 32;
      char* vd = sV + c * 144 + hf * 64;
#pragma unroll
      for (int i = 0; i < 4; ++i) *(uint4*)(vd + i * 16) = *(const uint4*)(vs + i * 8);
    }
    __syncthreads();

    // QK^T for this head
    f32x4 s[4][4];
    {
      bf16x8 kf[4];
#pragma unroll
      for (int n = 0; n < 4; ++n)
        kf[n] = *(const bf16x8*)(sK + (n * 16 + arow) * 528 + h * 64 + ahi * 16);
#pragma unroll
      for (int m = 0; m < 4; ++m)
#pragma unroll
        for (int n = 0; n < 4; ++n)
          s[m][n] = __builtin_amdgcn_mfma_f32_16x16x32_bf16(qa[m], kf[n],
                      (f32x4){0.f, 0.f, 0.f, 0.f}, 0, 0, 0);
    }
    // bias + pooled mask + key-validity
#pragma unroll
    for (int n = 0; n < 4; ++n) {
      int key = kb + n * 16 + arow;
      float mk = 0.f;
      if (key >= 181 && key < 230) mk = maskp[win * 49 + (key - 181)];
      bool kvalid = key < 230;
#pragma unroll
      for (int m = 0; m < 4; ++m) {
        f32x4 bfr = *(const f32x4*)(biasp + (h * 256 + key) * 64 + m * 16 + ahi * 4);
#pragma unroll
        for (int reg = 0; reg < 4; ++reg)
          s[m][n][reg] = kvalid ? (s[m][n][reg] + bfr[reg] + mk) : -1e30f;
      }
    }
    // online softmax; row q = m*16 + ahi*4 + reg; 16 lanes (same ahi) share a row
#pragma unroll
    for (int m = 0; m < 4; ++m) {
#pragma unroll
      for (int reg = 0; reg < 4; ++reg) {
        float mx = fmaxf(fmaxf(s[m][0][reg], s[m][1][reg]), fmaxf(s[m][2][reg], s[m][3][reg]));
#pragma unroll
        for (int d = 1; d < 16; d <<= 1) mx = fmaxf(mx, __shfl_xor(mx, d));
        float mold = mrun[m][reg];
        float mnew = fmaxf(mold, mx);
        float sc = __expf(mold - mnew);
        float rs = 0.f;
#pragma unroll
        for (int n = 0; n < 4; ++n) {
          float p = __expf(s[m][n][reg] - mnew);
          s[m][n][reg] = p;
          rs += p;
        }
#pragma unroll
        for (int d = 1; d < 16; d <<= 1) rs += __shfl_xor(rs, d);
        lrun[m][reg] = lrun[m][reg] * sc + rs;
        mrun[m][reg] = mnew;
        o[m][0][reg] *= sc;
        o[m][1][reg] *= sc;
      }
    }
    // P -> per-wave LDS (bf16, row-major [q][key])
#pragma unroll
    for (int m = 0; m < 4; ++m)
#pragma unroll
      for (int n = 0; n < 4; ++n) {
        char* base = myP + (m * 16 + ahi * 4) * 144 + (n * 16 + arow) * 2;
#pragma unroll
        for (int reg = 0; reg < 4; ++reg)
          *(unsigned short*)(base + reg * 144) = f2bf(s[m][n][reg]);
      }
    // PV
    bf16x8 vf[2][2];
#pragma unroll
    for (int n2 = 0; n2 < 2; ++n2)
#pragma unroll
      for (int kv = 0; kv < 2; ++kv)
        vf[n2][kv] = *(const bf16x8*)(sV + (h * 32 + n2 * 16 + arow) * 144 + kv * 64 + ahi * 16);
#pragma unroll
    for (int m = 0; m < 4; ++m)
#pragma unroll
      for (int kv = 0; kv < 2; ++kv) {
        bf16x8 pf = *(const bf16x8*)(myP + (m * 16 + arow) * 144 + kv * 64 + ahi * 16);
#pragma unroll
        for (int n2 = 0; n2 < 2; ++n2)
          o[m][n2] = __builtin_amdgcn_mfma_f32_16x16x32_bf16(pf, vf[n2][kv], o[m][n2], 0, 0, 0);
      }
  }
  __syncthreads();   // everyone done reading sK/sV
  // normalize + gather heads into sK as bf16 [64 q][256 c]
#pragma unroll
  for (int m = 0; m < 4; ++m)
#pragma unroll
    for (int n2 = 0; n2 < 2; ++n2)
#pragma unroll
      for (int reg = 0; reg < 4; ++reg) {
        int qrow = m * 16 + ahi * 4 + reg;
        float val = o[m][n2][reg] / lrun[m][reg];
        *(unsigned short*)(sK + qrow * 528 + (h * 32 + n2 * 16 + arow) * 2) = f2bf(val);
      }
  __syncthreads();
  for (int i = tid; i < 49 * 32; i += 512) {
    int r = i >> 5, seg = i & 31;
    *(uint4*)(Og + (unsigned)(w * 49 + r) * 256 + seg * 8) = *(const uint4*)(sK + r * 528 + seg * 16);
  }
}

// ---------------- output projection -> fp32 d_out ----------------
__global__ __launch_bounds__(256, 4) void proj_gemm(
    const unsigned short* __restrict__ Og, const float* __restrict__ pb,
    const unsigned short* __restrict__ WpP, float* __restrict__ out) {
  __shared__ char smem[64 * 528];
  int tid = threadIdx.x;
  {
    int r = tid >> 2, seg = tid & 3;
    const unsigned short* src = Og + (unsigned)(blockIdx.x * 64 + r) * 256 + seg * 64;
    char* dst = smem + r * 528 + seg * 128;
#pragma unroll
    for (int i = 0; i < 8; ++i)
      *(uint4*)(dst + i * 16) = *(const uint4*)(src + i * 8);
  }
  __syncthreads();
  int lane = tid & 63, wv = tid >> 6;
  f32x4 acc[4][4];
#pragma unroll
  for (int m = 0; m < 4; ++m)
#pragma unroll
    for (int n = 0; n < 4; ++n) acc[m][n] = (f32x4){0.f, 0.f, 0.f, 0.f};
  gemm_core(smem, WpP, wv * 4, lane, acc);

  int arow = lane & 15, ahi = lane >> 4;
#pragma unroll
  for (int n = 0; n < 4; ++n) {
    int c = wv * 64 + n * 16 + arow;
    float bc = pb[c];
#pragma unroll
    for (int m = 0; m < 4; ++m) {
      int g = blockIdx.x * 64 + m * 16 + ahi * 4;
#pragma unroll
      for (int reg = 0; reg < 4; ++reg)
        out[(unsigned)(g + reg) * 256 + c] = acc[m][n][reg] + bc;   // 64B runs, aligned
    }
  }
}

extern "C" void kernel_launch(void* const* d_in, const int* in_sizes, int n_in,
                              void* d_out, int out_size, void* d_ws, size_t ws_size,
                              hipStream_t stream) {
  (void)in_sizes; (void)n_in; (void)out_size;
  const float* x    = (const float*)d_in[0];
  const float* xe   = (const float*)d_in[1];
  const float* xp   = (const float*)d_in[2];
  const float* mask = (const float*)d_in[3];
  const float* qw   = (const float*)d_in[4];
  const float* qb   = (const float*)d_in[5];
  const float* kw   = (const float*)d_in[6];
  const float* kb   = (const float*)d_in[7];
  const float* vw   = (const float*)d_in[8];
  const float* vb   = (const float*)d_in[9];
  const float* pw   = (const float*)d_in[10];
  const float* pb   = (const float*)d_in[11];
  const float* rpb  = (const float*)d_in[12];
  const float* rpbp = (const float*)d_in[13];

  // workspace layout (bytes); total = 328,728,576 (~314 MiB)
  char* ws = (char*)d_ws;
  if (ws_size < 328728576ull) return;  // loud failure if scratch too small
  unsigned short* Wp  = (unsigned short*)(ws);                       // 4 x 65536 bf16
  float* biasp        = (float*)(ws + 524288);                       // 131072 f32
  unsigned short* Qg  = (unsigned short*)(ws + 1048576);             // 1024x64x256
  unsigned short* Kg  = (unsigned short*)(ws + 1048576 + 33554432);  // 1024x256x256
  unsigned short* Vtg = (unsigned short*)(ws + 1048576 + 33554432 + 134217728);
  unsigned short* Og  = (unsigned short*)(ws + 1048576 + 33554432 + 2 * 134217728);
  const unsigned short* WpQ = Wp;
  const unsigned short* WpK = Wp + 65536;
  const unsigned short* WpV = Wp + 131072;
  const unsigned short* WpP = Wp + 196608;

  hipLaunchKernelGGL(prep_weights, dim3(1024), dim3(256), 0, stream, qw, kw, vw, pw, Wp);
  hipLaunchKernelGGL(prep_bias,    dim3(512),  dim3(256), 0, stream, rpb, rpbp, biasp);
  hipLaunchKernelGGL(q_gemm,       dim3(1024), dim3(256), 0, stream, x, qb, WpQ, Qg);
  hipLaunchKernelGGL(kv_gemm,      dim3(4096), dim3(512), 0, stream,
                     x, xe, xp, kb, vb, WpK, WpV, Kg, Vtg);
  hipLaunchKernelGGL(attn_kernel,  dim3(1024), dim3(512), 0, stream,
                     Qg, Kg, Vtg, biasp, mask, Og);
  hipLaunchKernelGGL(proj_gemm,    dim3(784),  dim3(256), 0, stream, Og, pb, WpP, (float*)d_out);
}

// Round 8
// 688.128 us; speedup vs baseline: 1.0826x; 1.0826x over previous
//
#include <hip/hip_runtime.h>

typedef __attribute__((ext_vector_type(8))) __bf16 bf16x8;
typedef __attribute__((ext_vector_type(4))) float f32x4;

#define SCALE_Q 0.17677669529663687f

// np.nonzero of the rolled-window validity mask (4 x 7x7, E=3), ascending.
__constant__ int VALID_IND_C[132] = {
  4,5,6, 11,12,13, 18,19,20, 25,26,27,
  28,29,30,31,32,33,34, 35,36,37,38,39,40,41, 42,43,44,45,46,47,48,
  49,50,51, 56,57,58, 63,64,65, 70,71,72,
  77,78,79,80,81,82,83, 84,85,86,87,88,89,90, 91,92,93,94,95,96,97,
  98,99,100,101,102,103,104, 105,106,107,108,109,110,111, 112,113,114,115,116,117,118,
  123,124,125, 130,131,132, 137,138,139, 144,145,146,
  147,148,149,150,151,152,153, 154,155,156,157,158,159,160, 161,162,163,164,165,166,167,
  168,169,170, 175,176,177, 182,183,184, 189,190,191
};

__device__ __forceinline__ unsigned short f2bf(float f) {
  unsigned int u = __float_as_uint(f);
  u += 0x7fffu + ((u >> 16) & 1u);   // RNE; inputs finite
  return (unsigned short)(u >> 16);
}

__device__ __forceinline__ uint4 pack8(const float4 a, const float4 b) {
  uint4 r;
  r.x = (unsigned)f2bf(a.x) | ((unsigned)f2bf(a.y) << 16);
  r.y = (unsigned)f2bf(a.z) | ((unsigned)f2bf(a.w) << 16);
  r.z = (unsigned)f2bf(b.x) | ((unsigned)f2bf(b.y) << 16);
  r.w = (unsigned)f2bf(b.z) | ((unsigned)f2bf(b.w) << 16);
  return r;
}

// ---------------- prep: pack weights frag-major ----------------
// Wp[((cf*8+ks)*64+lane)*8+e] = W[cf*16+(lane&15)][ks*32+(lane>>4)*8+e]
__global__ void prep_weights(const float* __restrict__ qw, const float* __restrict__ kw,
                             const float* __restrict__ vw, const float* __restrict__ pw,
                             unsigned short* __restrict__ wp) {
  int gid = blockIdx.x * 256 + threadIdx.x;          // 0 .. 262143
  int wsel = gid >> 16;
  int d = gid & 65535;
  const float* W = wsel == 0 ? qw : wsel == 1 ? kw : wsel == 2 ? vw : pw;
  int e = d & 7, ln = (d >> 3) & 63, ks = (d >> 9) & 7, cf = d >> 12;
  int c = cf * 16 + (ln & 15);
  int k = ks * 32 + ((ln >> 4) << 3) + e;
  wp[gid] = f2bf(W[c * 256 + k]);
}

// ---------------- prep: bias_packed[h][q(64)][key(256)] ----------------
__global__ void prep_bias(const float* __restrict__ rpb, const float* __restrict__ rpbp,
                          float* __restrict__ biasp) {
  int idx = blockIdx.x * 256 + threadIdx.x;          // 0 .. 131071
  int key = idx & 255, q = (idx >> 8) & 63, h = idx >> 14;
  int qc = q < 49 ? q : 48;
  float v;
  if (key < 181)      v = rpb[(h * 49 + qc) * 181 + key];
  else if (key < 230) v = rpbp[(h * 49 + qc) * 49 + (key - 181)];
  else                v = -1e30f;
  biasp[idx] = v;
}

// window w, window-local row l (0..255; >=230 clamped) -> source row (256 floats)
__device__ __forceinline__ const float* kv_src_row(int w, int l, const float* x,
                                                   const float* xe, const float* xp) {
  if (l >= 230) l = 229;
  if (l < 49) {
    int b = w >> 8, win = w & 255;
    int wy = win >> 4, wx = win & 15;
    int iy = l / 7, ix = l - iy * 7;
    return x + (((b * 112 + wy * 7 + iy) * 112) + wx * 7 + ix) * 256;
  } else if (l < 181) {
    return xe + (w * 196 + VALID_IND_C[l - 49]) * 256;
  } else {
    return xp + (w * 49 + (l - 181)) * 256;
  }
}

// GEMM core: acc[4][4] += Stile(64x256 bf16, LDS stride 528B) @ Wp^T (4 nfrags)
__device__ __forceinline__ void gemm_core(const char* smem, const unsigned short* Wp,
                                          int nfbase, int lane, f32x4 acc[4][4]) {
  int arow = lane & 15, ahi = lane >> 4;
#pragma unroll
  for (int ks = 0; ks < 8; ++ks) {
    bf16x8 a[4];
#pragma unroll
    for (int m = 0; m < 4; ++m)
      a[m] = *(const bf16x8*)(smem + (m * 16 + arow) * 528 + ks * 64 + ahi * 16);
#pragma unroll
    for (int n = 0; n < 4; ++n) {
      bf16x8 b = *(const bf16x8*)(Wp + (((nfbase + n) * 8 + ks) * 64 + lane) * 8);
#pragma unroll
      for (int m = 0; m < 4; ++m)
        acc[m][n] = __builtin_amdgcn_mfma_f32_16x16x32_bf16(a[m], b, acc[m][n], 0, 0, 0);
    }
  }
}

// ---------------- K & V projection (fused), window-aligned 64-row tiles ----------------
// grid = 1024 windows * 4 sub-tiles. Single 36.9KB LDS buffer; K/V epilogues serialized.
// (512,4): 128 total regs (64 VGPR + 64 acc, measured r3) -> 2 blocks/CU.
__global__ __launch_bounds__(512, 4) void kv_gemm(
    const float* __restrict__ x, const float* __restrict__ xe, const float* __restrict__ xp,
    const float* __restrict__ kb, const float* __restrict__ vb,
    const unsigned short* __restrict__ WpK, const unsigned short* __restrict__ WpV,
    unsigned short* __restrict__ Kg, unsigned short* __restrict__ Vtg) {
  __shared__ char smem[256 * 144];   // staging (64*528=33.8KB) then K tile then V tile
  int tid = threadIdx.x;
  int w = blockIdx.x >> 2, sub = blockIdx.x & 3;
  {
    int r = tid >> 3, seg = tid & 7;   // 32 floats per thread
    const float* src = kv_src_row(w, sub * 64 + r, x, xe, xp) + seg * 32;
    char* dst = smem + r * 528 + seg * 64;
#pragma unroll
    for (int i = 0; i < 4; ++i) {
      float4 a = ((const float4*)src)[i * 2];
      float4 b = ((const float4*)src)[i * 2 + 1];
      *(uint4*)(dst + i * 16) = pack8(a, b);
    }
  }
  __syncthreads();
  int lane = tid & 63, wv = tid >> 6;
  bool isV = wv >= 4;
  int colq = wv & 3;
  const unsigned short* Wp = isV ? WpV : WpK;
  f32x4 acc[4][4];
#pragma unroll
  for (int m = 0; m < 4; ++m)
#pragma unroll
    for (int n = 0; n < 4; ++n) acc[m][n] = (f32x4){0.f, 0.f, 0.f, 0.f};
  gemm_core(smem, Wp, colq * 4, lane, acc);

  int arow = lane & 15, ahi = lane >> 4;
  const float* bias = isV ? vb : kb;
  __syncthreads();   // all A-tile reads done; smem reusable
  if (!isV) {        // K tile -> smem [key_local 64][c 256] stride 528
#pragma unroll
    for (int n = 0; n < 4; ++n) {
      int c = colq * 64 + n * 16 + arow;
      float bc = bias[c];
#pragma unroll
      for (int m = 0; m < 4; ++m)
#pragma unroll
        for (int reg = 0; reg < 4; ++reg)
          *(unsigned short*)(smem + (m * 16 + ahi * 4 + reg) * 528 + c * 2) =
              f2bf(acc[m][n][reg] + bc);
    }
  }
  __syncthreads();
  { // K copy-out: skip pad rows (>=230)
    int r = tid >> 3, seg = tid & 7;
    int grow = sub * 64 + r;
    if (grow < 230) {
      unsigned short* dst = Kg + ((unsigned)w * 256 + grow) * 256 + seg * 32;
      const char* s = smem + r * 528 + seg * 64;
#pragma unroll
      for (int i = 0; i < 4; ++i) *(uint4*)(dst + i * 8) = *(const uint4*)(s + i * 16);
    }
  }
  __syncthreads();
  if (isV) {         // V tile -> smem [c 256][key_local 64] stride 144
#pragma unroll
    for (int n = 0; n < 4; ++n) {
      int c = colq * 64 + n * 16 + arow;
      float bc = bias[c];
#pragma unroll
      for (int m = 0; m < 4; ++m)
#pragma unroll
        for (int reg = 0; reg < 4; ++reg)
          *(unsigned short*)(smem + c * 144 + (m * 16 + ahi * 4 + reg) * 2) =
              f2bf(acc[m][n][reg] + bc);
    }
  }
  __syncthreads();
  { // V copy-out: 256 c-rows x 128B, coalesced
    int c = tid >> 1, hf = tid & 1;
    unsigned short* dst = Vtg + ((unsigned)w * 256 + c) * 256 + sub * 64 + hf * 32;
    const char* s = smem + c * 144 + hf * 64;
#pragma unroll
    for (int i = 0; i < 4; ++i) *(uint4*)(dst + i * 8) = *(const uint4*)(s + i * 16);
  }
}

// ---------------- Q projection (per-window, padded to 64 rows), 256 thr ----------------
__global__ __launch_bounds__(256, 4) void q_gemm(
    const float* __restrict__ x, const float* __restrict__ qb,
    const unsigned short* __restrict__ WpQ, unsigned short* __restrict__ Qg) {
  __shared__ char smem[64 * 528];
  int tid = threadIdx.x;
  int w = blockIdx.x;
  int b = w >> 8, win = w & 255, wy = win >> 4, wx = win & 15;
  {
    int r = tid >> 2, seg = tid & 3;   // 64 floats per thread
    int rr = r < 49 ? r : 48;          // clamp pad rows
    int iy = rr / 7, ix = rr - iy * 7;
    const float* src = x + (((b * 112 + wy * 7 + iy) * 112) + wx * 7 + ix) * 256 + seg * 64;
    char* dst = smem + r * 528 + seg * 128;
#pragma unroll
    for (int i = 0; i < 8; ++i) {
      float4 a = ((const float4*)src)[i * 2];
      float4 bb = ((const float4*)src)[i * 2 + 1];
      *(uint4*)(dst + i * 16) = pack8(a, bb);
    }
  }
  __syncthreads();
  int lane = tid & 63, wv = tid >> 6;
  f32x4 acc[4][4];
#pragma unroll
  for (int m = 0; m < 4; ++m)
#pragma unroll
    for (int n = 0; n < 4; ++n) acc[m][n] = (f32x4){0.f, 0.f, 0.f, 0.f};
  gemm_core(smem, WpQ, wv * 4, lane, acc);

  int arow = lane & 15, ahi = lane >> 4;
  __syncthreads();
#pragma unroll
  for (int n = 0; n < 4; ++n) {
    int c = wv * 64 + n * 16 + arow;
    float bc = qb[c];
#pragma unroll
    for (int m = 0; m < 4; ++m)
#pragma unroll
      for (int reg = 0; reg < 4; ++reg)
        *(unsigned short*)(smem + (m * 16 + ahi * 4 + reg) * 528 + c * 2) =
            f2bf((acc[m][n][reg] + bc) * SCALE_Q);
  }
  __syncthreads();
  {
    int r = tid >> 2, seg = tid & 3;
    unsigned short* dst = Qg + (unsigned)(w * 64 + r) * 256 + seg * 64;
    const char* s = smem + r * 528 + seg * 128;
#pragma unroll
    for (int i = 0; i < 8; ++i) *(uint4*)(dst + i * 8) = *(const uint4*)(s + i * 16);
  }
}

// ---------------- fused attention v2: no K/V LDS, no P LDS, max-free softmax ----------
// Per wave = one head. S^T = mfma(K,Q): lane holds P[q=ql][keys 4a+reg (+16 kblk)].
// Slot->key bijection sigma(s)=4*(s>>3)+(s&3)+16*((s>>2)&1) makes the PV B-frag the
// lane's OWN packed exp outputs (zero cross-lane traffic); V A-frag loads use the same
// sigma (two 8B loads). Denominator: per-lane partials, one 2-shuffle reduce at end.
// Masked keys (>=230 or pooled-mask) get bias -1e30 -> exp -> 0. QK mfma inside the
// m-loop keeps live score regs at 8 (fits 128-reg budget -> 2 blocks/CU).
__global__ __launch_bounds__(512, 4) void attn_kernel(
    const unsigned short* __restrict__ Qg, const unsigned short* __restrict__ Kg,
    const unsigned short* __restrict__ Vtg, const float* __restrict__ biasp,
    const float* __restrict__ maskp, unsigned short* __restrict__ Og) {
  __shared__ char sOut[64 * 528];     // [q 64][c 256] bf16 output transpose buffer
  __shared__ float smask[49];
  int tid = threadIdx.x, lane = tid & 63, h = tid >> 6;
  int w = blockIdx.x, win = w & 255;
  int ql = lane & 15, a = lane >> 4, a4 = a * 4;
  if (tid < 49) smask[tid] = maskp[win * 49 + tid];
  __syncthreads();

  // Q B-frags: Q[q=m*16+ql][h*32 + a*8 + e]
  bf16x8 qa[4];
#pragma unroll
  for (int m = 0; m < 4; ++m)
    qa[m] = *(const bf16x8*)(Qg + ((unsigned)w * 64 + m * 16 + ql) * 256 + h * 32 + a * 8);

  f32x4 o[4][2];
  float psum[4];
#pragma unroll
  for (int m = 0; m < 4; ++m) {
    o[m][0] = (f32x4){0.f, 0.f, 0.f, 0.f};
    o[m][1] = (f32x4){0.f, 0.f, 0.f, 0.f};
    psum[m] = 0.f;
  }

  const unsigned short* Kb = Kg + (unsigned)w * 65536 + h * 32 + a * 8;
  const unsigned short* Vb = Vtg + (unsigned)w * 65536;
  const float* Bb = biasp + h * 16384;

  for (int t = 0; t < 8; ++t) {
    int kbase = t * 32;
    // K A-frags: row=key_local=ql, k -> c = h*32 + 8a + e
    bf16x8 kf[2];
#pragma unroll
    for (int kblk = 0; kblk < 2; ++kblk)
      kf[kblk] = *(const bf16x8*)(Kb + (unsigned)(kbase + kblk * 16 + ql) * 256);
    // V A-frags (sigma slots): keys {kbase+4a..+3} and {kbase+16+4a..+3}
    bf16x8 vf[2];
#pragma unroll
    for (int n2 = 0; n2 < 2; ++n2) {
      const unsigned short* vp = Vb + (unsigned)(h * 32 + n2 * 16 + ql) * 256 + kbase + a4;
      union { uint2 d[2]; bf16x8 v; } u;
      u.d[0] = *(const uint2*)vp;
      u.d[1] = *(const uint2*)(vp + 16);
      vf[n2] = u.v;
    }
    // pooled mask per (kblk, reg) — key depends on a,reg only; LDS-resident
    float mk[2][4];
#pragma unroll
    for (int kblk = 0; kblk < 2; ++kblk)
#pragma unroll
      for (int reg = 0; reg < 4; ++reg) {
        int key = kbase + kblk * 16 + a4 + reg;
        mk[kblk][reg] = (key >= 181 && key < 230) ? smask[key - 181] : 0.f;
      }
#pragma unroll
    for (int m = 0; m < 4; ++m) {
      // S^T tile: D[key][q], lane -> q=ql, keys kblk*16 + 4a + reg
      f32x4 s0 = __builtin_amdgcn_mfma_f32_16x16x32_bf16(kf[0], qa[m],
                   (f32x4){0.f, 0.f, 0.f, 0.f}, 0, 0, 0);
      f32x4 s1 = __builtin_amdgcn_mfma_f32_16x16x32_bf16(kf[1], qa[m],
                   (f32x4){0.f, 0.f, 0.f, 0.f}, 0, 0, 0);
      const float* brow = Bb + (unsigned)(m * 16 + ql) * 256 + kbase + a4;
      f32x4 b0 = *(const f32x4*)(brow);
      f32x4 b1 = *(const f32x4*)(brow + 16);
      float p[8];
#pragma unroll
      for (int reg = 0; reg < 4; ++reg) {
        p[reg]     = __expf(s0[reg] + b0[reg] + mk[0][reg]);
        p[4 + reg] = __expf(s1[reg] + b1[reg] + mk[1][reg]);
        psum[m] += p[reg] + p[4 + reg];
      }
      union { unsigned u[4]; bf16x8 v; } pf;
      pf.u[0] = (unsigned)f2bf(p[0]) | ((unsigned)f2bf(p[1]) << 16);
      pf.u[1] = (unsigned)f2bf(p[2]) | ((unsigned)f2bf(p[3]) << 16);
      pf.u[2] = (unsigned)f2bf(p[4]) | ((unsigned)f2bf(p[5]) << 16);
      pf.u[3] = (unsigned)f2bf(p[6]) | ((unsigned)f2bf(p[7]) << 16);
#pragma unroll
      for (int n2 = 0; n2 < 2; ++n2)
        o[m][n2] = __builtin_amdgcn_mfma_f32_16x16x32_bf16(vf[n2], pf.v, o[m][n2], 0, 0, 0);
    }
  }
  // finalize: reduce denominator across the 4 a-lanes of each q, normalize, transpose
#pragma unroll
  for (int m = 0; m < 4; ++m) {
    float v = psum[m];
    v += __shfl_xor(v, 16);
    v += __shfl_xor(v, 32);
    float inv = 1.0f / v;
#pragma unroll
    for (int n2 = 0; n2 < 2; ++n2)
#pragma unroll
      for (int reg = 0; reg < 4; ++reg) {
        int q = m * 16 + ql;
        int c = h * 32 + n2 * 16 + a4 + reg;
        *(unsigned short*)(sOut + q * 528 + c * 2) = f2bf(o[m][n2][reg] * inv);
      }
  }
  __syncthreads();
  for (int i = tid; i < 49 * 32; i += 512) {
    int r = i >> 5, seg = i & 31;
    *(uint4*)(Og + (unsigned)(w * 49 + r) * 256 + seg * 8) = *(const uint4*)(sOut + r * 528 + seg * 16);
  }
}

// ---------------- output projection -> fp32 d_out ----------------
__global__ __launch_bounds__(256, 4) void proj_gemm(
    const unsigned short* __restrict__ Og, const float* __restrict__ pb,
    const unsigned short* __restrict__ WpP, float* __restrict__ out) {
  __shared__ char smem[64 * 528];
  int tid = threadIdx.x;
  {
    int r = tid >> 2, seg = tid & 3;
    const unsigned short* src = Og + (unsigned)(blockIdx.x * 64 + r) * 256 + seg * 64;
    char* dst = smem + r * 528 + seg * 128;
#pragma unroll
    for (int i = 0; i < 8; ++i)
      *(uint4*)(dst + i * 16) = *(const uint4*)(src + i * 8);
  }
  __syncthreads();
  int lane = tid & 63, wv = tid >> 6;
  f32x4 acc[4][4];
#pragma unroll
  for (int m = 0; m < 4; ++m)
#pragma unroll
    for (int n = 0; n < 4; ++n) acc[m][n] = (f32x4){0.f, 0.f, 0.f, 0.f};
  gemm_core(smem, WpP, wv * 4, lane, acc);

  int arow = lane & 15, ahi = lane >> 4;
#pragma unroll
  for (int n = 0; n < 4; ++n) {
    int c = wv * 64 + n * 16 + arow;
    float bc = pb[c];
#pragma unroll
    for (int m = 0; m < 4; ++m) {
      int g = blockIdx.x * 64 + m * 16 + ahi * 4;
#pragma unroll
      for (int reg = 0; reg < 4; ++reg)
        out[(unsigned)(g + reg) * 256 + c] = acc[m][n][reg] + bc;   // 64B runs, aligned
    }
  }
}

extern "C" void kernel_launch(void* const* d_in, const int* in_sizes, int n_in,
                              void* d_out, int out_size, void* d_ws, size_t ws_size,
                              hipStream_t stream) {
  (void)in_sizes; (void)n_in; (void)out_size;
  const float* x    = (const float*)d_in[0];
  const float* xe   = (const float*)d_in[1];
  const float* xp   = (const float*)d_in[2];
  const float* mask = (const float*)d_in[3];
  const float* qw   = (const float*)d_in[4];
  const float* qb   = (const float*)d_in[5];
  const float* kw   = (const float*)d_in[6];
  const float* kb   = (const float*)d_in[7];
  const float* vw   = (const float*)d_in[8];
  const float* vb   = (const float*)d_in[9];
  const float* pw   = (const float*)d_in[10];
  const float* pb   = (const float*)d_in[11];
  const float* rpb  = (const float*)d_in[12];
  const float* rpbp = (const float*)d_in[13];

  // workspace layout (bytes); total = 328,728,576 (~314 MiB)
  char* ws = (char*)d_ws;
  if (ws_size < 328728576ull) return;  // loud failure if scratch too small
  unsigned short* Wp  = (unsigned short*)(ws);                       // 4 x 65536 bf16
  float* biasp        = (float*)(ws + 524288);                       // 131072 f32
  unsigned short* Qg  = (unsigned short*)(ws + 1048576);             // 1024x64x256
  unsigned short* Kg  = (unsigned short*)(ws + 1048576 + 33554432);  // 1024x256x256
  unsigned short* Vtg = (unsigned short*)(ws + 1048576 + 33554432 + 134217728);
  unsigned short* Og  = (unsigned short*)(ws + 1048576 + 33554432 + 2 * 134217728);
  const unsigned short* WpQ = Wp;
  const unsigned short* WpK = Wp + 65536;
  const unsigned short* WpV = Wp + 131072;
  const unsigned short* WpP = Wp + 196608;

  hipLaunchKernelGGL(prep_weights, dim3(1024), dim3(256), 0, stream, qw, kw, vw, pw, Wp);
  hipLaunchKernelGGL(prep_bias,    dim3(512),  dim3(256), 0, stream, rpb, rpbp, biasp);
  hipLaunchKernelGGL(q_gemm,       dim3(1024), dim3(256), 0, stream, x, qb, WpQ, Qg);
  hipLaunchKernelGGL(kv_gemm,      dim3(4096), dim3(512), 0, stream,
                     x, xe, xp, kb, vb, WpK, WpV, Kg, Vtg);
  hipLaunchKernelGGL(attn_kernel,  dim3(1024), dim3(512), 0, stream,
                     Qg, Kg, Vtg, biasp, mask, Og);
  hipLaunchKernelGGL(proj_gemm,    dim3(784),  dim3(256), 0, stream, Og, pb, WpP, (float*)d_out);
}